// Round 2
// baseline (1252.480 us; speedup 1.0000x reference)
//
#include <hip/hip_runtime.h>
#include <hip/hip_bf16.h>

typedef short bf16x8 __attribute__((ext_vector_type(8)));
typedef float f32x4 __attribute__((ext_vector_type(4)));

#define SEQ 4096
#define DDIM 1024
#define NBATCH 4

// ---------------- enc [b][e][d] fp32 -> encT [b][d][e] bf16 ----------------
__global__ __launch_bounds__(256) void transpose_bf16(const float* __restrict__ src,
                                                      __hip_bfloat16* __restrict__ dst) {
  __shared__ float tile[32][33];
  int b = blockIdx.z;
  int e0 = blockIdx.x * 32, d0 = blockIdx.y * 32;
  const float* s = src + (size_t)b * SEQ * DDIM;
  __hip_bfloat16* dt = dst + (size_t)b * DDIM * SEQ;
  int tx = threadIdx.x & 31, ty = threadIdx.x >> 5;  // ty in 0..7
#pragma unroll
  for (int i = 0; i < 4; i++) {
    int e = e0 + ty + i * 8;
    tile[ty + i * 8][tx] = s[(size_t)e * DDIM + d0 + tx];
  }
  __syncthreads();
#pragma unroll
  for (int i = 0; i < 4; i++) {
    int d = d0 + ty + i * 8;
    dt[(size_t)d * SEQ + e0 + tx] = __float2bfloat16(tile[tx][ty + i * 8]);
  }
}

#define BM 128
#define BN 128
#define BK 64
#define LDK 72  // padded LDS row stride in bf16 elems

// ---------------- split-precision GEMM1: S[M][N] = A[M][K] * B[N][K]^T ------
// A,B fp32 in global; split to (hi,lo) bf16 during staging.
// S = Ah*Bh^T + Ah*Bl^T + Al*Bh^T   (lo*lo dropped, ~2^-18 relative)
__global__ __launch_bounds__(256) void gemm1_split(const float* __restrict__ A,
                                                   const float* __restrict__ B,
                                                   float* __restrict__ C, int M, int N, int K) {
  __shared__ __align__(16) __hip_bfloat16 AsH[BM * LDK];
  __shared__ __align__(16) __hip_bfloat16 AsL[BM * LDK];
  __shared__ __align__(16) __hip_bfloat16 BsH[BM * LDK];
  __shared__ __align__(16) __hip_bfloat16 BsL[BM * LDK];
  const int tid = threadIdx.x;
  const int bm = blockIdx.x, bn = blockIdx.y;
  const int wave = tid >> 6, lane = tid & 63;
  const int wm = (wave & 1) * 64, wn = (wave >> 1) * 64;
  const int mrow = lane & 15, quad = lane >> 4;

  f32x4 acc[4][4];
#pragma unroll
  for (int i = 0; i < 4; i++)
#pragma unroll
    for (int j = 0; j < 4; j++) acc[i][j] = {0.f, 0.f, 0.f, 0.f};

  const float* Ag = A + (size_t)(bm * BM) * K;
  const float* Bg = B + (size_t)(bn * BN) * K;

  for (int k0 = 0; k0 < K; k0 += BK) {
    // each tile: 128 rows x 64 fp32 = 2048 float4 chunks; 8 chunks/thread/tile
#pragma unroll
    for (int i = 0; i < 8; i++) {
      int cid = i * 256 + tid;
      int row = cid >> 4, ch = cid & 15;  // ch indexes float4 within row
      float4 va = *(const float4*)(Ag + (size_t)row * K + k0 + ch * 4);
      float4 vb = *(const float4*)(Bg + (size_t)row * K + k0 + ch * 4);
      union { ushort4 u; __hip_bfloat16 h[4]; } ah, al, bh, bl;
      float av[4] = {va.x, va.y, va.z, va.w};
      float bv[4] = {vb.x, vb.y, vb.z, vb.w};
#pragma unroll
      for (int e = 0; e < 4; e++) {
        __hip_bfloat16 h = __float2bfloat16(av[e]);
        ah.h[e] = h;
        al.h[e] = __float2bfloat16(av[e] - __bfloat162float(h));
        h = __float2bfloat16(bv[e]);
        bh.h[e] = h;
        bl.h[e] = __float2bfloat16(bv[e] - __bfloat162float(h));
      }
      *(ushort4*)(&AsH[row * LDK + ch * 4]) = ah.u;
      *(ushort4*)(&AsL[row * LDK + ch * 4]) = al.u;
      *(ushort4*)(&BsH[row * LDK + ch * 4]) = bh.u;
      *(ushort4*)(&BsL[row * LDK + ch * 4]) = bl.u;
    }
    __syncthreads();
#pragma unroll
    for (int ks = 0; ks < 2; ks++) {
      bf16x8 afh[4], afl[4], bfh[4], bfl[4];
#pragma unroll
      for (int i = 0; i < 4; i++) {
        int ao = (wm + i * 16 + mrow) * LDK + ks * 32 + quad * 8;
        int bo = (wn + i * 16 + mrow) * LDK + ks * 32 + quad * 8;
        afh[i] = *(const bf16x8*)(&AsH[ao]);
        afl[i] = *(const bf16x8*)(&AsL[ao]);
        bfh[i] = *(const bf16x8*)(&BsH[bo]);
        bfl[i] = *(const bf16x8*)(&BsL[bo]);
      }
#pragma unroll
      for (int mi = 0; mi < 4; mi++)
#pragma unroll
        for (int ni = 0; ni < 4; ni++) {
          acc[mi][ni] =
              __builtin_amdgcn_mfma_f32_16x16x32_bf16(afh[mi], bfh[ni], acc[mi][ni], 0, 0, 0);
          acc[mi][ni] =
              __builtin_amdgcn_mfma_f32_16x16x32_bf16(afh[mi], bfl[ni], acc[mi][ni], 0, 0, 0);
          acc[mi][ni] =
              __builtin_amdgcn_mfma_f32_16x16x32_bf16(afl[mi], bfh[ni], acc[mi][ni], 0, 0, 0);
        }
    }
    __syncthreads();
  }
#pragma unroll
  for (int mi = 0; mi < 4; mi++) {
#pragma unroll
    for (int ni = 0; ni < 4; ni++) {
      int row0 = bm * BM + wm + mi * 16 + quad * 4;
      int col = bn * BN + wn + ni * 16 + mrow;
      float* Cp = C + (size_t)row0 * N + col;
#pragma unroll
      for (int r = 0; r < 4; r++) Cp[(size_t)r * N] = acc[mi][ni][r];
    }
  }
}

// ---------------- bf16 BT GEMM (GEMM2): C[M][N] = A[M][K] * B[N][K]^T -------
__global__ __launch_bounds__(256) void gemm_bt(const __hip_bfloat16* __restrict__ A,
                                               const __hip_bfloat16* __restrict__ B,
                                               float* __restrict__ C, int M, int N, int K) {
  __shared__ __align__(16) __hip_bfloat16 As[BM * LDK];
  __shared__ __align__(16) __hip_bfloat16 Bs[BN * LDK];
  const int tid = threadIdx.x;
  const int bm = blockIdx.x, bn = blockIdx.y;
  const int wave = tid >> 6, lane = tid & 63;
  const int wm = (wave & 1) * 64, wn = (wave >> 1) * 64;
  const int mrow = lane & 15, quad = lane >> 4;

  f32x4 acc[4][4];
#pragma unroll
  for (int i = 0; i < 4; i++)
#pragma unroll
    for (int j = 0; j < 4; j++) acc[i][j] = {0.f, 0.f, 0.f, 0.f};

  const __hip_bfloat16* Ag = A + (size_t)(bm * BM) * K;
  const __hip_bfloat16* Bg = B + (size_t)(bn * BN) * K;

  for (int k0 = 0; k0 < K; k0 += BK) {
#pragma unroll
    for (int i = 0; i < 4; i++) {
      int cid = i * 256 + tid;
      int row = cid >> 3, ch = cid & 7;
      *(int4*)(&As[row * LDK + ch * 8]) = *(const int4*)(Ag + (size_t)row * K + k0 + ch * 8);
      *(int4*)(&Bs[row * LDK + ch * 8]) = *(const int4*)(Bg + (size_t)row * K + k0 + ch * 8);
    }
    __syncthreads();
#pragma unroll
    for (int ks = 0; ks < 2; ks++) {
      bf16x8 af[4], bfr[4];
#pragma unroll
      for (int i = 0; i < 4; i++) {
        af[i] = *(const bf16x8*)(&As[(wm + i * 16 + mrow) * LDK + ks * 32 + quad * 8]);
        bfr[i] = *(const bf16x8*)(&Bs[(wn + i * 16 + mrow) * LDK + ks * 32 + quad * 8]);
      }
#pragma unroll
      for (int mi = 0; mi < 4; mi++)
#pragma unroll
        for (int ni = 0; ni < 4; ni++)
          acc[mi][ni] =
              __builtin_amdgcn_mfma_f32_16x16x32_bf16(af[mi], bfr[ni], acc[mi][ni], 0, 0, 0);
    }
    __syncthreads();
  }
#pragma unroll
  for (int mi = 0; mi < 4; mi++) {
#pragma unroll
    for (int ni = 0; ni < 4; ni++) {
      int row0 = bm * BM + wm + mi * 16 + quad * 4;
      int col = bn * BN + wn + ni * 16 + mrow;
      float* Cp = C + (size_t)row0 * N + col;
#pragma unroll
      for (int r = 0; r < 4; r++) Cp[(size_t)r * N] = acc[mi][ni][r];
    }
  }
}

// ---------------- row softmax: S[t][:] fp32 -> P[t][:] bf16 ----------------
__global__ __launch_bounds__(256) void softmax_rows(const float* __restrict__ S,
                                                    __hip_bfloat16* __restrict__ P) {
  const int row = blockIdx.x;
  const float4* Sr = (const float4*)(S + (size_t)row * SEQ);
  const int tid = threadIdx.x, lane = tid & 63, wave = tid >> 6;
  __shared__ float red[4];
  __shared__ float bc;
  float4 v[4];
  float m = -1e30f;
#pragma unroll
  for (int j = 0; j < 4; j++) {
    v[j] = Sr[tid + j * 256];
    m = fmaxf(m, fmaxf(fmaxf(v[j].x, v[j].y), fmaxf(v[j].z, v[j].w)));
  }
#pragma unroll
  for (int o = 32; o; o >>= 1) m = fmaxf(m, __shfl_xor(m, o));
  if (lane == 0) red[wave] = m;
  __syncthreads();
  if (tid == 0) bc = fmaxf(fmaxf(red[0], red[1]), fmaxf(red[2], red[3]));
  __syncthreads();
  m = bc;
  float s = 0.f;
#pragma unroll
  for (int j = 0; j < 4; j++) {
    v[j].x = __expf(v[j].x - m);
    v[j].y = __expf(v[j].y - m);
    v[j].z = __expf(v[j].z - m);
    v[j].w = __expf(v[j].w - m);
    s += v[j].x + v[j].y + v[j].z + v[j].w;
  }
#pragma unroll
  for (int o = 32; o; o >>= 1) s += __shfl_xor(s, o);
  __syncthreads();
  if (lane == 0) red[wave] = s;
  __syncthreads();
  if (tid == 0) bc = red[0] + red[1] + red[2] + red[3];
  __syncthreads();
  float r = 1.0f / bc;
  ushort4* Pr = (ushort4*)(P + (size_t)row * SEQ);
#pragma unroll
  for (int j = 0; j < 4; j++) {
    union { ushort4 u; __hip_bfloat16 h[4]; } o;
    o.h[0] = __float2bfloat16(v[j].x * r);
    o.h[1] = __float2bfloat16(v[j].y * r);
    o.h[2] = __float2bfloat16(v[j].z * r);
    o.h[3] = __float2bfloat16(v[j].w * r);
    Pr[tid + j * 256] = o.u;
  }
}

// ---------------- naive fp32 fallback (no workspace needed) ----------------
__global__ __launch_bounds__(256) void naive_attn(const float* __restrict__ enc,
                                                  const float* __restrict__ dec,
                                                  float* __restrict__ out) {
  const int b = blockIdx.y, t = blockIdx.x;
  const float* encb = enc + (size_t)b * SEQ * DDIM;
  const float* q = dec + ((size_t)b * SEQ + t) * DDIM;
  __shared__ float qs[DDIM];
  __shared__ float sc[SEQ];
  __shared__ float red[4];
  __shared__ float bc;
  const int tid = threadIdx.x, lane = tid & 63, wave = tid >> 6;
  for (int i = tid; i < DDIM; i += 256) qs[i] = q[i];
  __syncthreads();
  for (int e = tid; e < SEQ; e += 256) {
    const float* er = encb + (size_t)e * DDIM;
    float s = 0.f;
    for (int d = 0; d < DDIM; d += 4) {
      float4 ev = *(const float4*)(er + d);
      s += ev.x * qs[d] + ev.y * qs[d + 1] + ev.z * qs[d + 2] + ev.w * qs[d + 3];
    }
    sc[e] = s;
  }
  __syncthreads();
  float m = -1e30f;
  for (int e = tid; e < SEQ; e += 256) m = fmaxf(m, sc[e]);
#pragma unroll
  for (int o = 32; o; o >>= 1) m = fmaxf(m, __shfl_xor(m, o));
  if (lane == 0) red[wave] = m;
  __syncthreads();
  if (tid == 0) bc = fmaxf(fmaxf(red[0], red[1]), fmaxf(red[2], red[3]));
  __syncthreads();
  m = bc;
  float s = 0.f;
  for (int e = tid; e < SEQ; e += 256) {
    float p = __expf(sc[e] - m);
    sc[e] = p;
    s += p;
  }
#pragma unroll
  for (int o = 32; o; o >>= 1) s += __shfl_xor(s, o);
  __syncthreads();
  if (lane == 0) red[wave] = s;
  __syncthreads();
  if (tid == 0) bc = red[0] + red[1] + red[2] + red[3];
  __syncthreads();
  const float rinv = 1.0f / bc;
  const int d0 = tid * 4;
  float4 acc = {0.f, 0.f, 0.f, 0.f};
  for (int e = 0; e < SEQ; e++) {
    float p = sc[e];
    float4 ev = *(const float4*)(encb + (size_t)e * DDIM + d0);
    acc.x += p * ev.x;
    acc.y += p * ev.y;
    acc.z += p * ev.z;
    acc.w += p * ev.w;
  }
  float4* o4 = (float4*)(out + ((size_t)b * SEQ + t) * DDIM + d0);
  float4 res = {acc.x * rinv, acc.y * rinv, acc.z * rinv, acc.w * rinv};
  *o4 = res;
}

extern "C" void kernel_launch(void* const* d_in, const int* in_sizes, int n_in, void* d_out,
                              int out_size, void* d_ws, size_t ws_size, hipStream_t stream) {
  const float* enc = (const float*)d_in[0];
  const float* dec = (const float*)d_in[1];
  float* out = (float*)d_out;

  const size_t SZ_S = (size_t)SEQ * SEQ * 4;              // 64 MiB
  const size_t SZ_P = (size_t)SEQ * SEQ * 2;              // 32 MiB
  const size_t SZ_ET = (size_t)NBATCH * SEQ * DDIM * 2;   // 32 MiB
  const size_t NEED = SZ_S + SZ_P + SZ_ET;                // 128 MiB

  if (ws_size >= NEED) {
    char* w = (char*)d_ws;
    float* S = (float*)w;
    __hip_bfloat16* P = (__hip_bfloat16*)(w + SZ_S);
    __hip_bfloat16* encT = (__hip_bfloat16*)(w + SZ_S + SZ_P);

    transpose_bf16<<<dim3(SEQ / 32, DDIM / 32, NBATCH), 256, 0, stream>>>(enc, encT);

    for (int b = 0; b < NBATCH; b++) {
      const size_t eo = (size_t)b * SEQ * DDIM;
      // S[t][e] = dec[t]·enc[e] at near-fp32 precision (split bf16)
      gemm1_split<<<dim3(SEQ / BM, SEQ / BN), 256, 0, stream>>>(dec + eo, enc + eo, S, SEQ, SEQ,
                                                                DDIM);
      softmax_rows<<<SEQ, 256, 0, stream>>>(S, P);
      // out[t][d] = sum_e P[t][e] * encT[d][e]
      gemm_bt<<<dim3(SEQ / BM, DDIM / BN), 256, 0, stream>>>(P, encT + (size_t)b * DDIM * SEQ,
                                                             out + eo, SEQ, DDIM, SEQ);
    }
  } else {
    naive_attn<<<dim3(SEQ, NBATCH), 256, 0, stream>>>(enc, dec, out);
  }
}

// Round 3
// 773.099 us; speedup vs baseline: 1.6201x; 1.6201x over previous
//
#include <hip/hip_runtime.h>
#include <hip/hip_fp16.h>

typedef _Float16 half_t;
typedef _Float16 f16x8 __attribute__((ext_vector_type(8)));
typedef _Float16 f16x4 __attribute__((ext_vector_type(4)));
typedef float f32x4 __attribute__((ext_vector_type(4)));

#define SEQ 4096
#define DDIM 1024
#define NBATCH 4

// async global->LDS, 16B per lane. LDS dest is wave-uniform base + lane*16,
// so the per-lane lds pointer MUST be base + lane*16 in wave-lane order.
__device__ __forceinline__ void gload16(const half_t* g, half_t* l) {
  __builtin_amdgcn_global_load_lds((const __attribute__((address_space(1))) void*)g,
                                   (__attribute__((address_space(3))) void*)l, 16, 0, 0);
}

// ---------------- fp32 -> fp16 elementwise convert ----------------
__global__ __launch_bounds__(256) void conv_f16(const float* __restrict__ src,
                                                half_t* __restrict__ dst) {
  int i = blockIdx.x * 256 + threadIdx.x;
  float4 x = ((const float4*)src)[i];
  f16x4 o = {(half_t)x.x, (half_t)x.y, (half_t)x.z, (half_t)x.w};
  *(f16x4*)(dst + (size_t)i * 4) = o;
}

// ---------------- enc [b][e][d] fp32 -> encT [b][d][e] fp16 ----------------
__global__ __launch_bounds__(256) void transpose_f16(const float* __restrict__ src,
                                                     half_t* __restrict__ dst) {
  __shared__ float tile[32][33];
  int b = blockIdx.z;
  int e0 = blockIdx.x * 32, d0 = blockIdx.y * 32;
  const float* s = src + (size_t)b * SEQ * DDIM;
  half_t* dt = dst + (size_t)b * DDIM * SEQ;
  int tx = threadIdx.x & 31, ty = threadIdx.x >> 5;
#pragma unroll
  for (int i = 0; i < 4; i++) {
    int e = e0 + ty + i * 8;
    tile[ty + i * 8][tx] = s[(size_t)e * DDIM + d0 + tx];
  }
  __syncthreads();
#pragma unroll
  for (int i = 0; i < 4; i++) {
    int d = d0 + ty + i * 8;
    dt[(size_t)d * SEQ + e0 + tx] = (half_t)tile[tx][ty + i * 8];
  }
}

// ---------------- fp16 BT GEMM: C[M][N] fp32 = A[M][K] * B[N][K]^T ----------
// m97 structure: 128x128 tile, BK=64, global_load_lds width-16 staging,
// unpadded LDS + XOR chunk swizzle (slot = chunk ^ (row&7)) for conflict-free
// ds_read_b128 fragments. 256 thr = 4 waves (2x2 of 64x64).
#define BM 128
#define BN 128
#define BK 64

__global__ __launch_bounds__(256) void gemm_f16(const half_t* __restrict__ A,
                                                const half_t* __restrict__ B,
                                                float* __restrict__ C, int M, int N, int K) {
  __shared__ __align__(16) half_t As[BM * BK];
  __shared__ __align__(16) half_t Bs[BN * BK];
  const int tid = threadIdx.x;
  const int bm = blockIdx.x, bn = blockIdx.y;
  const int wave = tid >> 6, lane = tid & 63;
  const int wm = (wave & 1) * 64, wn = (wave >> 1) * 64;
  const int mrow = lane & 15, quad = lane >> 4;

  f32x4 acc[4][4];
#pragma unroll
  for (int i = 0; i < 4; i++)
#pragma unroll
    for (int j = 0; j < 4; j++) acc[i][j] = {0.f, 0.f, 0.f, 0.f};

  const half_t* Ag = A + (size_t)(bm * BM) * K;
  const half_t* Bg = B + (size_t)(bn * BN) * K;

  // staging geometry: tile = 128 rows x 8 chunks(16B); cid = i*256 + tid
  // row = cid>>3, slot = cid&7, global chunk = slot ^ (row&7)
  for (int k0 = 0; k0 < K; k0 += BK) {
#pragma unroll
    for (int i = 0; i < 4; i++) {
      int cid = i * 256 + tid;
      int row = cid >> 3, slot = cid & 7;
      int chunk = slot ^ (row & 7);
      gload16(Ag + (size_t)row * K + k0 + chunk * 8, &As[row * BK + slot * 8]);
      gload16(Bg + (size_t)row * K + k0 + chunk * 8, &Bs[row * BK + slot * 8]);
    }
    __builtin_amdgcn_s_waitcnt(0);
    __syncthreads();
#pragma unroll
    for (int ks = 0; ks < 2; ks++) {
      f16x8 af[4], bf[4];
#pragma unroll
      for (int i = 0; i < 4; i++) {
        int ra = wm + i * 16 + mrow;
        int rb = wn + i * 16 + mrow;
        int sa = (ks * 4 + quad) ^ (ra & 7);
        int sb = (ks * 4 + quad) ^ (rb & 7);
        af[i] = *(const f16x8*)(&As[ra * BK + sa * 8]);
        bf[i] = *(const f16x8*)(&Bs[rb * BK + sb * 8]);
      }
#pragma unroll
      for (int mi = 0; mi < 4; mi++)
#pragma unroll
        for (int ni = 0; ni < 4; ni++)
          acc[mi][ni] =
              __builtin_amdgcn_mfma_f32_16x16x32_f16(af[mi], bf[ni], acc[mi][ni], 0, 0, 0);
    }
    __syncthreads();
  }
  // epilogue: D[row=(quad*4+r)][col=lane&15] per 16x16 tile [measured m89/m91]
#pragma unroll
  for (int mi = 0; mi < 4; mi++) {
#pragma unroll
    for (int ni = 0; ni < 4; ni++) {
      int row0 = bm * BM + wm + mi * 16 + quad * 4;
      int col = bn * BN + wn + ni * 16 + mrow;
      float* Cp = C + (size_t)row0 * N + col;
#pragma unroll
      for (int r = 0; r < 4; r++) Cp[(size_t)r * N] = acc[mi][ni][r];
    }
  }
}

// ---------------- row softmax: S[t][:] fp32 -> P[t][:] fp16 ----------------
__global__ __launch_bounds__(256) void softmax_rows(const float* __restrict__ S,
                                                    half_t* __restrict__ P) {
  const int row = blockIdx.x;
  const float4* Sr = (const float4*)(S + (size_t)row * SEQ);
  const int tid = threadIdx.x, lane = tid & 63, wave = tid >> 6;
  __shared__ float red[4];
  __shared__ float bc;
  float4 v[4];
  float m = -1e30f;
#pragma unroll
  for (int j = 0; j < 4; j++) {
    v[j] = Sr[tid + j * 256];
    m = fmaxf(m, fmaxf(fmaxf(v[j].x, v[j].y), fmaxf(v[j].z, v[j].w)));
  }
#pragma unroll
  for (int o = 32; o; o >>= 1) m = fmaxf(m, __shfl_xor(m, o));
  if (lane == 0) red[wave] = m;
  __syncthreads();
  if (tid == 0) bc = fmaxf(fmaxf(red[0], red[1]), fmaxf(red[2], red[3]));
  __syncthreads();
  m = bc;
  float s = 0.f;
#pragma unroll
  for (int j = 0; j < 4; j++) {
    v[j].x = __expf(v[j].x - m);
    v[j].y = __expf(v[j].y - m);
    v[j].z = __expf(v[j].z - m);
    v[j].w = __expf(v[j].w - m);
    s += v[j].x + v[j].y + v[j].z + v[j].w;
  }
#pragma unroll
  for (int o = 32; o; o >>= 1) s += __shfl_xor(s, o);
  __syncthreads();
  if (lane == 0) red[wave] = s;
  __syncthreads();
  if (tid == 0) bc = red[0] + red[1] + red[2] + red[3];
  __syncthreads();
  float r = 1.0f / bc;
  f16x4* Pr = (f16x4*)(P + (size_t)row * SEQ);
#pragma unroll
  for (int j = 0; j < 4; j++) {
    f16x4 o = {(half_t)(v[j].x * r), (half_t)(v[j].y * r), (half_t)(v[j].z * r),
               (half_t)(v[j].w * r)};
    Pr[tid + j * 256] = o;
  }
}

// ---------------- naive fp32 fallback (no workspace needed) ----------------
__global__ __launch_bounds__(256) void naive_attn(const float* __restrict__ enc,
                                                  const float* __restrict__ dec,
                                                  float* __restrict__ out) {
  const int b = blockIdx.y, t = blockIdx.x;
  const float* encb = enc + (size_t)b * SEQ * DDIM;
  const float* q = dec + ((size_t)b * SEQ + t) * DDIM;
  __shared__ float qs[DDIM];
  __shared__ float sc[SEQ];
  __shared__ float red[4];
  __shared__ float bc;
  const int tid = threadIdx.x, lane = tid & 63, wave = tid >> 6;
  for (int i = tid; i < DDIM; i += 256) qs[i] = q[i];
  __syncthreads();
  for (int e = tid; e < SEQ; e += 256) {
    const float* er = encb + (size_t)e * DDIM;
    float s = 0.f;
    for (int d = 0; d < DDIM; d += 4) {
      float4 ev = *(const float4*)(er + d);
      s += ev.x * qs[d] + ev.y * qs[d + 1] + ev.z * qs[d + 2] + ev.w * qs[d + 3];
    }
    sc[e] = s;
  }
  __syncthreads();
  float m = -1e30f;
  for (int e = tid; e < SEQ; e += 256) m = fmaxf(m, sc[e]);
#pragma unroll
  for (int o = 32; o; o >>= 1) m = fmaxf(m, __shfl_xor(m, o));
  if (lane == 0) red[wave] = m;
  __syncthreads();
  if (tid == 0) bc = fmaxf(fmaxf(red[0], red[1]), fmaxf(red[2], red[3]));
  __syncthreads();
  m = bc;
  float s = 0.f;
  for (int e = tid; e < SEQ; e += 256) {
    float p = __expf(sc[e] - m);
    sc[e] = p;
    s += p;
  }
#pragma unroll
  for (int o = 32; o; o >>= 1) s += __shfl_xor(s, o);
  __syncthreads();
  if (lane == 0) red[wave] = s;
  __syncthreads();
  if (tid == 0) bc = red[0] + red[1] + red[2] + red[3];
  __syncthreads();
  const float rinv = 1.0f / bc;
  const int d0 = tid * 4;
  float4 acc = {0.f, 0.f, 0.f, 0.f};
  for (int e = 0; e < SEQ; e++) {
    float p = sc[e];
    float4 ev = *(const float4*)(encb + (size_t)e * DDIM + d0);
    acc.x += p * ev.x;
    acc.y += p * ev.y;
    acc.z += p * ev.z;
    acc.w += p * ev.w;
  }
  float4* o4 = (float4*)(out + ((size_t)b * SEQ + t) * DDIM + d0);
  float4 res = {acc.x * rinv, acc.y * rinv, acc.z * rinv, acc.w * rinv};
  *o4 = res;
}

extern "C" void kernel_launch(void* const* d_in, const int* in_sizes, int n_in, void* d_out,
                              int out_size, void* d_ws, size_t ws_size, hipStream_t stream) {
  const float* enc = (const float*)d_in[0];
  const float* dec = (const float*)d_in[1];
  float* out = (float*)d_out;

  const size_t SZ_S = (size_t)SEQ * SEQ * 4;             // 64 MiB
  const size_t SZ_P = (size_t)SEQ * SEQ * 2;             // 32 MiB
  const size_t SZ_H = (size_t)NBATCH * SEQ * DDIM * 2;   // 32 MiB each
  const size_t NEED = SZ_S + SZ_P + 3 * SZ_H;            // 192 MiB (proven available R1)

  if (ws_size >= NEED) {
    char* w = (char*)d_ws;
    float* S = (float*)w;
    half_t* P = (half_t*)(w + SZ_S);
    half_t* decF = (half_t*)(w + SZ_S + SZ_P);
    half_t* encF = (half_t*)(w + SZ_S + SZ_P + SZ_H);
    half_t* encT = (half_t*)(w + SZ_S + SZ_P + 2 * SZ_H);

    const int nconv = NBATCH * SEQ * DDIM / 4 / 256;  // 16384 blocks
    conv_f16<<<nconv, 256, 0, stream>>>(dec, decF);
    conv_f16<<<nconv, 256, 0, stream>>>(enc, encF);
    transpose_f16<<<dim3(SEQ / 32, DDIM / 32, NBATCH), 256, 0, stream>>>(enc, encT);

    for (int b = 0; b < NBATCH; b++) {
      const size_t eo = (size_t)b * SEQ * DDIM;
      // S[t][e] = dec[t]·enc[e]
      gemm_f16<<<dim3(SEQ / BM, SEQ / BN), 256, 0, stream>>>(decF + eo, encF + eo, S, SEQ, SEQ,
                                                             DDIM);
      softmax_rows<<<SEQ, 256, 0, stream>>>(S, P);
      // out[t][d] = sum_e P[t][e] * encT[d][e]
      gemm_f16<<<dim3(SEQ / BM, DDIM / BN), 256, 0, stream>>>(P, encT + eo, out + eo, SEQ, DDIM,
                                                              SEQ);
    }
  } else {
    naive_attn<<<dim3(SEQ, NBATCH), 256, 0, stream>>>(enc, dec, out);
  }
}